// Round 11
// baseline (2674.848 us; speedup 1.0000x reference)
//
#include <hip/hip_runtime.h>
#include <hip/hip_fp8.h>
#include <math.h>

#define B_ROWS 2048
#define D_K    2048
#define N_CLS  50257
#define BM     256
#define BN     128
#define BKB    64               // K-bytes per step (fp8)
#define NT     (D_K / BKB)      // 32 K-steps
#define GM     8                // 2048/256 m-tiles
#define GN     393              // ceil(50257/128) n-tiles
#define N_PAD  (GN * BN)        // 50304
#define NWG    (GM * GN)        // 3144 = 8*393 (bijective XCD swizzle)

// LDS: DOUBLE buffer, 24KB each. Buffer b at b*24576:
//   A [256 rows][64 B] at +0 (16KB), B [128 rows][64 B] at +16384 (8KB).
// 16-B slot swizzle within each 64-B row: position p = content_slot ^ ((row>>1)&3).
// Stats (6KB) OVERLAY buffer 0 — only live after the K-loop's final barrier.
#define ABY    16384
#define BUFB   24576

typedef __attribute__((ext_vector_type(4)))  int   i32x4;
typedef __attribute__((ext_vector_type(8)))  int   i32x8;
typedef __attribute__((ext_vector_type(16))) float f32x16;

typedef __attribute__((address_space(1))) const void as1cv;
typedef __attribute__((address_space(3))) void       as3v;

__device__ __forceinline__ void glds16(const void* g, void* l) {
  __builtin_amdgcn_global_load_lds((as1cv*)g, (as3v*)l, 16, 0, 0);
}

__device__ __forceinline__ unsigned char f2q(float x) {
  __hip_fp8_e4m3 q(x);
  return *reinterpret_cast<unsigned char*>(&q);
}

// ---------- W: fp32 -> fp8 e4m3, scaled x128, zero-padded to N_PAD rows ----------
__global__ void conv_w_q(const float* __restrict__ W, unsigned char* __restrict__ Wq) {
  const size_t NU = (size_t)N_PAD * D_K / 8;
  const size_t stride = (size_t)gridDim.x * blockDim.x;
  for (size_t u = (size_t)blockIdx.x * blockDim.x + threadIdx.x; u < NU; u += stride) {
    const size_t e = u * 8;
    unsigned long long pk = 0ull;
    if ((e >> 11) < (size_t)N_CLS) {
      const float4 a = *(const float4*)(W + e);
      const float4 b = *(const float4*)(W + e + 4);
      const float v[8] = {a.x, a.y, a.z, a.w, b.x, b.y, b.z, b.w};
#pragma unroll
      for (int i = 0; i < 8; ++i)
        pk |= (unsigned long long)f2q(v[i] * 128.0f) << (8 * i);
    }
    *(unsigned long long*)(Wq + e) = pk;
  }
}

// ---------- E: fp32 -> fp8 e4m3, row-major ----------
__global__ void conv_e_q(const float* __restrict__ E, unsigned char* __restrict__ Eq) {
  const size_t NU = (size_t)B_ROWS * D_K / 8;
  const size_t stride = (size_t)gridDim.x * blockDim.x;
  for (size_t u = (size_t)blockIdx.x * blockDim.x + threadIdx.x; u < NU; u += stride) {
    const size_t e = u * 8;
    const float4 a = *(const float4*)(E + e);
    const float4 b = *(const float4*)(E + e + 4);
    const float v[8] = {a.x, a.y, a.z, a.w, b.x, b.y, b.z, b.w};
    unsigned long long pk = 0ull;
#pragma unroll
    for (int i = 0; i < 8; ++i)
      pk |= (unsigned long long)f2q(v[i]) << (8 * i);
    *(unsigned long long*)(Eq + e) = pk;
  }
}

// ---------- fused MX-fp8 GEMM + per-tile row stats ----------
// 256x128 tile, 4 waves (2m x 2n), per-wave 128x64 via 4x2 mfma_scale 32x32x64.
// R10 loop structure (prefetch-then-compute, 1 barrier/step); 48KB LDS ->
// 3 blocks/CU for implicit multi-block overlap (m114/m148).
__global__ __launch_bounds__(256, 3) void gemm_ce(
    const unsigned char* __restrict__ Eq,
    const unsigned char* __restrict__ Wq,
    const int* __restrict__ labels,
    float* __restrict__ pm, float* __restrict__ ps, float* __restrict__ pt,
    float* __restrict__ ly)
{
  __shared__ __align__(16) char lds[2 * BUFB];
  // stats overlay (live only after K-loop):
  float (*s_m)[2] = (float (*)[2])(lds);
  float (*s_s)[2] = (float (*)[2])(lds + 2048);
  float (*s_t)[2] = (float (*)[2])(lds + 4096);

  const int tid  = threadIdx.x;
  const int wid  = tid >> 6;
  const int lane = tid & 63;
  const int wm   = wid >> 1;       // 0..1 -> 128-row block
  const int wn   = wid & 1;        // 0..1 -> 64-col block
  const int l31  = lane & 31;
  const int lh   = lane >> 5;      // 0..1 -> k-half of the 64-B step

  // XCD-aware bijective swizzle (NWG = 8*393); 8 consecutive logicals share
  // the B panel and land on one XCD.
  const int bid     = blockIdx.x;
  const int logical = (bid & 7) * (NWG / 8) + (bid >> 3);
  const int n_tile  = logical / GM;
  const int m_tile  = logical % GM;

  // ---- staging: thread t writes dest byte q*4096 + t*16
  //      row = q*64 + (t>>2), slot position = t&3
  //      content slot = (t&3) ^ ((row>>1)&3) = (t&3) ^ ((t>>3)&3)  (q*32 ≡ 0 mod 4)
  const int gsw  = (((tid & 3) ^ ((tid >> 3) & 3)) << 4);
  const int srow = tid >> 2;
  const unsigned char* Ag = Eq + (size_t)(m_tile * BM + srow) * D_K + gsw;
  const unsigned char* Bg = Wq + (size_t)(n_tile * BN + srow) * D_K + gsw;
  const int sdst = tid * 16;
  // +q -> +64 rows = +131072 B global; +K-step -> +64 B

  // ---- fragment read offsets (32x32x64): lane reads row R = base + l31,
  //      k-bytes lh*32..+31 -> content slots 2lh, 2lh+1;
  //      position = slot ^ ((R>>1)&3), (R>>1)&3 = (l31>>1)&3 (base ≡ 0 mod 8)
  const int rmsk = (l31 >> 1) & 3;
  int offA[4][2], offB[2][2];
#pragma unroll
  for (int fi = 0; fi < 4; ++fi)
#pragma unroll
    for (int rd = 0; rd < 2; ++rd)
      offA[fi][rd] = (wm * 128 + fi * 32 + l31) * 64 + (((lh * 2 + rd) ^ rmsk) << 4);
#pragma unroll
  for (int fj = 0; fj < 2; ++fj)
#pragma unroll
    for (int rd = 0; rd < 2; ++rd)
      offB[fj][rd] = ABY + (wn * 64 + fj * 32 + l31) * 64 + (((lh * 2 + rd) ^ rmsk) << 4);

  f32x16 acc[4][2] = {};
  union FR { i32x8 v; i32x4 h[2]; };

#define STAGE(BUF, TT)                                                     \
  do {                                                                     \
    const unsigned char* _a = Ag + (size_t)(TT) * BKB;                     \
    const unsigned char* _b = Bg + (size_t)(TT) * BKB;                     \
    char* _d = lds + (BUF) * BUFB + sdst;                                  \
    _Pragma("unroll")                                                      \
    for (int q = 0; q < 4; ++q)                                            \
      glds16(_a + (size_t)q * 131072, _d + q * 4096);                      \
    _Pragma("unroll")                                                      \
    for (int q = 0; q < 2; ++q)                                            \
      glds16(_b + (size_t)q * 131072, _d + ABY + q * 4096);                \
  } while (0)

  // prologue: stage tile 0 into buf0, drain, sync
  STAGE(0, 0);
  __syncthreads();

  for (int t = 0; t < NT; ++t) {
    const char* Rb = lds + (t & 1) * BUFB;

    if (t < NT - 1) STAGE((t + 1) & 1, t + 1);   // prefetch next step

    FR fa[4], fb[2];
#pragma unroll
    for (int fi = 0; fi < 4; ++fi) {
      fa[fi].h[0] = *(const i32x4*)(Rb + offA[fi][0]);
      fa[fi].h[1] = *(const i32x4*)(Rb + offA[fi][1]);
    }
#pragma unroll
    for (int fj = 0; fj < 2; ++fj) {
      fb[fj].h[0] = *(const i32x4*)(Rb + offB[fj][0]);
      fb[fj].h[1] = *(const i32x4*)(Rb + offB[fj][1]);
    }
#pragma unroll
    for (int fi = 0; fi < 4; ++fi)
#pragma unroll
      for (int fj = 0; fj < 2; ++fj)
        acc[fi][fj] = __builtin_amdgcn_mfma_scale_f32_32x32x64_f8f6f4(
            fa[fi].v, fb[fj].v, acc[fi][fj], 0, 0,
            0, 0x7F7F7F7F, 0, 0x7F7F7F7F);

    // end of step: implicit vmcnt(0)+lgkmcnt(0)+barrier drains the prefetch
    __syncthreads();
  }
#undef STAGE

  // ---------- epilogue: per-row (max, sumexp, sum) + label gather ----------
  // C/D 32x32: col = lane&31, row = (reg&3) + 8*(reg>>2) + 4*(lane>>5)  [m74/m101]
  const float inv = 0.0078125f;   // 1/128 (undo W pre-scale)
  const int colb = n_tile * BN + wn * 64;
  const int c0_  = colb + l31;
  const int c1_  = c0_ + 32;
  const bool ok0 = c0_ < N_CLS;
  const bool ok1 = c1_ < N_CLS;

#pragma unroll
  for (int fi = 0; fi < 4; ++fi) {
#pragma unroll
    for (int reg = 0; reg < 16; ++reg) {
      const int rt  = wm * 128 + fi * 32 + (reg & 3) + 8 * (reg >> 2) + 4 * lh;
      const int row = m_tile * BM + rt;
      const float v0 = acc[fi][0][reg] * inv;
      const float v1 = acc[fi][1][reg] * inv;
      const int lab = labels[row];
      if (lab == c0_) ly[row] = v0;
      if (lab == c1_) ly[row] = v1;

      float mx = fmaxf(ok0 ? v0 : -INFINITY, ok1 ? v1 : -INFINITY);
      float sm = (ok0 ? v0 : 0.f) + (ok1 ? v1 : 0.f);
#pragma unroll
      for (int d = 1; d < 32; d <<= 1) {
        mx = fmaxf(mx, __shfl_xor(mx, d));
        sm += __shfl_xor(sm, d);
      }
      float se = (ok0 ? __expf(v0 - mx) : 0.f) + (ok1 ? __expf(v1 - mx) : 0.f);
#pragma unroll
      for (int d = 1; d < 32; d <<= 1) se += __shfl_xor(se, d);

      if (l31 == 0) { s_m[rt][wn] = mx; s_s[rt][wn] = se; s_t[rt][wn] = sm; }
    }
  }
  __syncthreads();
  if (tid < BM) {
    const float m0 = s_m[tid][0], m1 = s_m[tid][1];
    const float M = fmaxf(m0, m1);
    const float S = s_s[tid][0] * __expf(m0 - M) + s_s[tid][1] * __expf(m1 - M);
    const float T = s_t[tid][0] + s_t[tid][1];
    const size_t o = (size_t)n_tile * B_ROWS + m_tile * BM + tid;
    pm[o] = M; ps[o] = S; pt[o] = T;
  }
}

// ---------- final combine: GN partials per row -> loss ----------
__global__ void ce_reduce(const float* __restrict__ pm, const float* __restrict__ ps,
                          const float* __restrict__ pt, const float* __restrict__ ly,
                          float* __restrict__ out)
{
  const int tid = threadIdx.x;
  const int row = blockIdx.x * blockDim.x + tid;
  float M = -INFINITY, S = 0.f, T = 0.f;
  for (int nt = 0; nt < GN; ++nt) {
    const size_t o = (size_t)nt * B_ROWS + row;
    const float m = pm[o], s = ps[o], t = pt[o];
    const float Mn = fmaxf(M, m);
    S = S * __expf(M - Mn) + s * __expf(m - Mn);
    M = Mn;
    T += t;
  }
  const float lse = M + logf(S);
  float per = lse - 0.9f * ly[row] - 0.1f * (T * (1.0f / (float)N_CLS));
#pragma unroll
  for (int d = 1; d < 64; d <<= 1) per += __shfl_xor(per, d);
  __shared__ float red[4];
  if ((tid & 63) == 0) red[tid >> 6] = per;
  __syncthreads();
  if (tid == 0)
    atomicAdd(out, (red[0] + red[1] + red[2] + red[3]) * (1.0f / B_ROWS));
}

extern "C" void kernel_launch(void* const* d_in, const int* in_sizes, int n_in,
                              void* d_out, int out_size, void* d_ws, size_t ws_size,
                              hipStream_t stream)
{
  const float* E      = (const float*)d_in[0];
  const int*   labels = (const int*)  d_in[1];
  const float* W      = (const float*)d_in[2];
  float* out = (float*)d_out;

  char* ws = (char*)d_ws;
  unsigned char* Wq = (unsigned char*)ws;
  size_t off = (size_t)N_PAD * D_K;                // 103,022,592 B
  unsigned char* Eq = (unsigned char*)(ws + off);
  off += (size_t)B_ROWS * D_K;                     // + 4,194,304 B
  float* pm = (float*)(ws + off); off += (size_t)GN * B_ROWS * 4;
  float* ps = (float*)(ws + off); off += (size_t)GN * B_ROWS * 4;
  float* pt = (float*)(ws + off); off += (size_t)GN * B_ROWS * 4;
  float* ly = (float*)(ws + off);                  // total ~117 MB

  hipMemsetAsync(d_out, 0, sizeof(float), stream);
  conv_w_q<<<dim3(2048), dim3(256), 0, stream>>>(W, Wq);
  conv_e_q<<<dim3(512),  dim3(256), 0, stream>>>(E, Eq);
  gemm_ce<<<dim3(NWG), dim3(256), 0, stream>>>(Eq, Wq, labels, pm, ps, pt, ly);
  ce_reduce<<<dim3(B_ROWS / 256), dim3(256), 0, stream>>>(pm, ps, pt, ly, out);
}

// Round 12
// 2241.787 us; speedup vs baseline: 1.1932x; 1.1932x over previous
//
#include <hip/hip_runtime.h>
#include <hip/hip_fp8.h>
#include <math.h>

#define B_ROWS 2048
#define D_K    2048
#define N_CLS  50257
#define BM     256
#define BN     128
#define BKB    64               // K-bytes per step (fp8)
#define NT     (D_K / BKB)      // 32 K-steps
#define GM     8                // 2048/256 m-tiles
#define GN     393              // ceil(50257/128) n-tiles
#define N_PAD  (GN * BN)        // 50304
#define NWG    (GM * GN)        // 3144 = 8*393 (bijective XCD swizzle)

// LDS: DOUBLE buffer, 24KB each. Buffer b at b*24576:
//   A [256 rows][64 B] at +0 (16KB), B [128 rows][64 B] at +16384 (8KB).
// 16-B slot swizzle within each 64-B row: position p = content_slot ^ ((row>>1)&3).
// Stats (3KB) OVERLAY buffer 0 — only live after the K-loop's final barrier.
#define ABY    16384
#define BUFB   24576

typedef __attribute__((ext_vector_type(4)))  int   i32x4;
typedef __attribute__((ext_vector_type(8)))  int   i32x8;
typedef __attribute__((ext_vector_type(16))) float f32x16;

typedef __attribute__((address_space(1))) const void as1cv;
typedef __attribute__((address_space(3))) void       as3v;

__device__ __forceinline__ void glds16(const void* g, void* l) {
  __builtin_amdgcn_global_load_lds((as1cv*)g, (as3v*)l, 16, 0, 0);
}

__device__ __forceinline__ unsigned char f2q(float x) {
  __hip_fp8_e4m3 q(x);
  return *reinterpret_cast<unsigned char*>(&q);
}

// ---------- W: fp32 -> fp8 e4m3, scaled x128, zero-padded to N_PAD rows ----------
__global__ void conv_w_q(const float* __restrict__ W, unsigned char* __restrict__ Wq) {
  const size_t NU = (size_t)N_PAD * D_K / 8;
  const size_t stride = (size_t)gridDim.x * blockDim.x;
  for (size_t u = (size_t)blockIdx.x * blockDim.x + threadIdx.x; u < NU; u += stride) {
    const size_t e = u * 8;
    unsigned long long pk = 0ull;
    if ((e >> 11) < (size_t)N_CLS) {
      const float4 a = *(const float4*)(W + e);
      const float4 b = *(const float4*)(W + e + 4);
      const float v[8] = {a.x, a.y, a.z, a.w, b.x, b.y, b.z, b.w};
#pragma unroll
      for (int i = 0; i < 8; ++i)
        pk |= (unsigned long long)f2q(v[i] * 128.0f) << (8 * i);
    }
    *(unsigned long long*)(Wq + e) = pk;
  }
}

// ---------- E: fp32 -> fp8 e4m3, row-major ----------
__global__ void conv_e_q(const float* __restrict__ E, unsigned char* __restrict__ Eq) {
  const size_t NU = (size_t)B_ROWS * D_K / 8;
  const size_t stride = (size_t)gridDim.x * blockDim.x;
  for (size_t u = (size_t)blockIdx.x * blockDim.x + threadIdx.x; u < NU; u += stride) {
    const size_t e = u * 8;
    const float4 a = *(const float4*)(E + e);
    const float4 b = *(const float4*)(E + e + 4);
    const float v[8] = {a.x, a.y, a.z, a.w, b.x, b.y, b.z, b.w};
    unsigned long long pk = 0ull;
#pragma unroll
    for (int i = 0; i < 8; ++i)
      pk |= (unsigned long long)f2q(v[i]) << (8 * i);
    *(unsigned long long*)(Eq + e) = pk;
  }
}

// ---------- fused MX-fp8 GEMM + per-tile row stats ----------
// 256x128 tile, 4 waves (2m x 2n), per-wave 128x64 via 4x2 mfma_scale 32x32x64.
// Prefetch-then-compute, 1 barrier/step. NO launch_bounds wave floor:
// acc = 128 AGPR/thread, forcing 3 blocks/CU spills the accumulator (R11).
__global__ __launch_bounds__(256) void gemm_ce(
    const unsigned char* __restrict__ Eq,
    const unsigned char* __restrict__ Wq,
    const int* __restrict__ labels,
    float* __restrict__ pm, float* __restrict__ ps, float* __restrict__ pt,
    float* __restrict__ ly)
{
  __shared__ __align__(16) char lds[2 * BUFB];
  // stats overlay (live only after K-loop):
  float (*s_m)[2] = (float (*)[2])(lds);
  float (*s_s)[2] = (float (*)[2])(lds + 2048);
  float (*s_t)[2] = (float (*)[2])(lds + 4096);

  const int tid  = threadIdx.x;
  const int wid  = tid >> 6;
  const int lane = tid & 63;
  const int wm   = wid >> 1;       // 0..1 -> 128-row block
  const int wn   = wid & 1;        // 0..1 -> 64-col block
  const int l31  = lane & 31;
  const int lh   = lane >> 5;      // 0..1 -> k-half of the 64-B step

  // XCD-aware bijective swizzle (NWG = 8*393); 8 consecutive logicals share
  // the B panel and land on one XCD.
  const int bid     = blockIdx.x;
  const int logical = (bid & 7) * (NWG / 8) + (bid >> 3);
  const int n_tile  = logical / GM;
  const int m_tile  = logical % GM;

  // ---- staging: thread t writes dest byte q*4096 + t*16
  //      row = q*64 + (t>>2), slot position = t&3
  //      content slot = (t&3) ^ ((row>>1)&3) = (t&3) ^ ((t>>3)&3)
  const int gsw  = (((tid & 3) ^ ((tid >> 3) & 3)) << 4);
  const int srow = tid >> 2;
  const unsigned char* Ag = Eq + (size_t)(m_tile * BM + srow) * D_K + gsw;
  const unsigned char* Bg = Wq + (size_t)(n_tile * BN + srow) * D_K + gsw;
  const int sdst = tid * 16;
  // +q -> +64 rows = +131072 B global; +K-step -> +64 B

  // ---- fragment read offsets (32x32x64): lane reads row R = base + l31,
  //      k-bytes lh*32..+31 -> content slots 2lh, 2lh+1;
  //      position = slot ^ ((R>>1)&3), (R>>1)&3 = (l31>>1)&3
  const int rmsk = (l31 >> 1) & 3;
  int offA[4][2], offB[2][2];
#pragma unroll
  for (int fi = 0; fi < 4; ++fi)
#pragma unroll
    for (int rd = 0; rd < 2; ++rd)
      offA[fi][rd] = (wm * 128 + fi * 32 + l31) * 64 + (((lh * 2 + rd) ^ rmsk) << 4);
#pragma unroll
  for (int fj = 0; fj < 2; ++fj)
#pragma unroll
    for (int rd = 0; rd < 2; ++rd)
      offB[fj][rd] = ABY + (wn * 64 + fj * 32 + l31) * 64 + (((lh * 2 + rd) ^ rmsk) << 4);

  f32x16 acc[4][2] = {};
  union FR { i32x8 v; i32x4 h[2]; };

#define STAGE(BUF, TT)                                                     \
  do {                                                                     \
    const unsigned char* _a = Ag + (size_t)(TT) * BKB;                     \
    const unsigned char* _b = Bg + (size_t)(TT) * BKB;                     \
    char* _d = lds + (BUF) * BUFB + sdst;                                  \
    _Pragma("unroll")                                                      \
    for (int q = 0; q < 4; ++q)                                            \
      glds16(_a + (size_t)q * 131072, _d + q * 4096);                      \
    _Pragma("unroll")                                                      \
    for (int q = 0; q < 2; ++q)                                            \
      glds16(_b + (size_t)q * 131072, _d + ABY + q * 4096);                \
  } while (0)

  // prologue: stage tile 0 into buf0, drain, sync
  STAGE(0, 0);
  __syncthreads();

  for (int t = 0; t < NT; ++t) {
    const char* Rb = lds + (t & 1) * BUFB;

    if (t < NT - 1) STAGE((t + 1) & 1, t + 1);   // prefetch next step

    FR fa[4], fb[2];
#pragma unroll
    for (int fi = 0; fi < 4; ++fi) {
      fa[fi].h[0] = *(const i32x4*)(Rb + offA[fi][0]);
      fa[fi].h[1] = *(const i32x4*)(Rb + offA[fi][1]);
    }
#pragma unroll
    for (int fj = 0; fj < 2; ++fj) {
      fb[fj].h[0] = *(const i32x4*)(Rb + offB[fj][0]);
      fb[fj].h[1] = *(const i32x4*)(Rb + offB[fj][1]);
    }
#pragma unroll
    for (int fi = 0; fi < 4; ++fi)
#pragma unroll
      for (int fj = 0; fj < 2; ++fj)
        acc[fi][fj] = __builtin_amdgcn_mfma_scale_f32_32x32x64_f8f6f4(
            fa[fi].v, fb[fj].v, acc[fi][fj], 0, 0,
            0, 0x7F7F7F7F, 0, 0x7F7F7F7F);

    // end of step: implicit vmcnt(0)+lgkmcnt(0)+barrier drains the prefetch
    __syncthreads();
  }
#undef STAGE

  // ---------- epilogue: per-row (max, sumexp, sum) + label gather ----------
  // C/D 32x32: col = lane&31, row = (reg&3) + 8*(reg>>2) + 4*(lane>>5)  [m74/m101]
  const float inv = 0.0078125f;   // 1/128 (undo W pre-scale)
  const int colb = n_tile * BN + wn * 64;
  const int c0_  = colb + l31;
  const int c1_  = c0_ + 32;
  const bool ok0 = c0_ < N_CLS;
  const bool ok1 = c1_ < N_CLS;

#pragma unroll
  for (int fi = 0; fi < 4; ++fi) {
#pragma unroll
    for (int reg = 0; reg < 16; ++reg) {
      const int rt  = wm * 128 + fi * 32 + (reg & 3) + 8 * (reg >> 2) + 4 * lh;
      const int row = m_tile * BM + rt;
      const float v0 = acc[fi][0][reg] * inv;
      const float v1 = acc[fi][1][reg] * inv;
      const int lab = labels[row];
      if (lab == c0_) ly[row] = v0;
      if (lab == c1_) ly[row] = v1;

      float mx = fmaxf(ok0 ? v0 : -INFINITY, ok1 ? v1 : -INFINITY);
      float sm = (ok0 ? v0 : 0.f) + (ok1 ? v1 : 0.f);
#pragma unroll
      for (int d = 1; d < 32; d <<= 1) {
        mx = fmaxf(mx, __shfl_xor(mx, d));
        sm += __shfl_xor(sm, d);
      }
      float se = (ok0 ? __expf(v0 - mx) : 0.f) + (ok1 ? __expf(v1 - mx) : 0.f);
#pragma unroll
      for (int d = 1; d < 32; d <<= 1) se += __shfl_xor(se, d);

      if (l31 == 0) { s_m[rt][wn] = mx; s_s[rt][wn] = se; s_t[rt][wn] = sm; }
    }
  }
  __syncthreads();
  if (tid < BM) {
    const float m0 = s_m[tid][0], m1 = s_m[tid][1];
    const float M = fmaxf(m0, m1);
    const float S = s_s[tid][0] * __expf(m0 - M) + s_s[tid][1] * __expf(m1 - M);
    const float T = s_t[tid][0] + s_t[tid][1];
    const size_t o = (size_t)n_tile * B_ROWS + m_tile * BM + tid;
    pm[o] = M; ps[o] = S; pt[o] = T;
  }
}

// ---------- final combine: GN partials per row -> loss ----------
__global__ void ce_reduce(const float* __restrict__ pm, const float* __restrict__ ps,
                          const float* __restrict__ pt, const float* __restrict__ ly,
                          float* __restrict__ out)
{
  const int tid = threadIdx.x;
  const int row = blockIdx.x * blockDim.x + tid;
  float M = -INFINITY, S = 0.f, T = 0.f;
  for (int nt = 0; nt < GN; ++nt) {
    const size_t o = (size_t)nt * B_ROWS + row;
    const float m = pm[o], s = ps[o], t = pt[o];
    const float Mn = fmaxf(M, m);
    S = S * __expf(M - Mn) + s * __expf(m - Mn);
    M = Mn;
    T += t;
  }
  const float lse = M + logf(S);
  float per = lse - 0.9f * ly[row] - 0.1f * (T * (1.0f / (float)N_CLS));
#pragma unroll
  for (int d = 1; d < 64; d <<= 1) per += __shfl_xor(per, d);
  __shared__ float red[4];
  if ((tid & 63) == 0) red[tid >> 6] = per;
  __syncthreads();
  if (tid == 0)
    atomicAdd(out, (red[0] + red[1] + red[2] + red[3]) * (1.0f / B_ROWS));
}

extern "C" void kernel_launch(void* const* d_in, const int* in_sizes, int n_in,
                              void* d_out, int out_size, void* d_ws, size_t ws_size,
                              hipStream_t stream)
{
  const float* E      = (const float*)d_in[0];
  const int*   labels = (const int*)  d_in[1];
  const float* W      = (const float*)d_in[2];
  float* out = (float*)d_out;

  char* ws = (char*)d_ws;
  unsigned char* Wq = (unsigned char*)ws;
  size_t off = (size_t)N_PAD * D_K;                // 103,022,592 B
  unsigned char* Eq = (unsigned char*)(ws + off);
  off += (size_t)B_ROWS * D_K;                     // + 4,194,304 B
  float* pm = (float*)(ws + off); off += (size_t)GN * B_ROWS * 4;
  float* ps = (float*)(ws + off); off += (size_t)GN * B_ROWS * 4;
  float* pt = (float*)(ws + off); off += (size_t)GN * B_ROWS * 4;
  float* ly = (float*)(ws + off);                  // total ~117 MB

  hipMemsetAsync(d_out, 0, sizeof(float), stream);
  conv_w_q<<<dim3(2048), dim3(256), 0, stream>>>(W, Wq);
  conv_e_q<<<dim3(512),  dim3(256), 0, stream>>>(E, Eq);
  gemm_ce<<<dim3(NWG), dim3(256), 0, stream>>>(Eq, Wq, labels, pm, ps, pt, ly);
  ce_reduce<<<dim3(B_ROWS / 256), dim3(256), 0, stream>>>(pm, ps, pt, ly, out);
}